// Round 7
// baseline (266.841 us; speedup 1.0000x reference)
//
#include <hip/hip_runtime.h>

namespace {
constexpr int N_ = 8, C_ = 32, H_ = 256, W_ = 512, DISP_ = 25;
constexpr int CH = H_ * W_;          // elements between channels / disparities
constexpr int SU = 4;                // channels staged per superstep
constexpr int NSU = C_ / SU;         // 8 supersteps
constexpr int LDS_BUF = SU * 2 * W_; // floats per LDS buffer (4096)
}

// 4-group disparity split + double-buffered LDS staging.
// 512 threads/block = one (n,h) row:
//   t = tid & 127 -> 4 output columns (w0 = 4t)
//   G = tid >> 7  -> disparity group (wave-uniform):
//     G0: i in [0,7)  G1: [7,13)  G2: [13,19)  G3: [19,25)
// Staging role is also G-derived (compile-time): array = G&1 (x/y),
// channels = G>>1 and G>>1 + 2. 2 float4/thread/superstep -> global traffic
// is the compulsory minimum; window redundancy served from LDS.
// Double-buffered LDS (32 KB) -> ONE barrier per superstep; next superstep's
// global loads issue a full compute phase ahead (HBM latency hidden).
// Register budget (round-3/6 post-mortem: spills are the killer):
// acc 28 + st 8 + yv/xv 16 + addr ~18 = ~70 < 85 cap of launch_bounds(512,6).
template <int G>
__device__ __forceinline__ void body(const float* __restrict__ stage_src,
                                     float* __restrict__ op,
                                     float* __restrict__ lds,
                                     const int* yoff, int w0, int t) {
  constexpr int I0 = (G == 0) ? 0 : (G == 1) ? 7 : (G == 2) ? 13 : 19;
  constexpr int NI = (G == 0) ? 7 : 6;
  constexpr int OFF = (G == 0) ? 4 : (G == 1) ? 0 : (G == 2) ? -8 : -12;
  constexpr int CC0 = G >> 1;  // first staged channel within superstep
  constexpr int ARR = G & 1;   // 0 -> stages x rows, 1 -> stages y rows

  float acc[NI][4];
#pragma unroll
  for (int il = 0; il < NI; ++il)
#pragma unroll
    for (int cw = 0; cw < 4; ++cw) acc[il][cw] = 0.0f;

  float4 st[2];

#define LOADSS(su)                                                         \
  do {                                                                     \
    st[0] = *reinterpret_cast<const float4*>(stage_src +                   \
                                             (size_t)((su)*SU + CC0) * CH); \
    st[1] = *reinterpret_cast<const float4*>(                              \
        stage_src + (size_t)((su)*SU + CC0 + 2) * CH);                     \
  } while (0)

#define WRITESS(b)                                                         \
  do {                                                                     \
    *reinterpret_cast<float4*>(lds + (b)*LDS_BUF + (CC0 * 2 + ARR) * W_ +  \
                               4 * t) = st[0];                             \
    *reinterpret_cast<float4*>(lds + (b)*LDS_BUF +                         \
                               ((CC0 + 2) * 2 + ARR) * W_ + 4 * t) = st[1];\
  } while (0)

  // Prologue: stage superstep 0 into buffer 0.
  LOADSS(0);
  WRITESS(0);
  __syncthreads();
  LOADSS(1);

#pragma unroll 1
  for (int su = 0; su < NSU; ++su) {
    // Write next superstep into the other buffer (waits on its global loads,
    // issued one full compute phase ago), then issue the loads after that.
    if (su + 1 < NSU) WRITESS((su + 1) & 1);
    if (su + 2 < NSU) LOADSS(su + 2);

    const float* bp = lds + (su & 1) * LDS_BUF;
#pragma unroll
    for (int cc = 0; cc < SU; ++cc) {
      const float* lx = bp + (cc * 2 + 0) * W_;
      const float* ly = bp + (cc * 2 + 1) * W_;
      const float4 xv = *reinterpret_cast<const float4*>(lx + w0);
      float4 yv[3];
#pragma unroll
      for (int k = 0; k < 3; ++k)
        yv[k] = *reinterpret_cast<const float4*>(ly + yoff[k]);

      const float xs[4] = {xv.x, xv.y, xv.z, xv.w};
      const float ywin[12] = {yv[0].x, yv[0].y, yv[0].z, yv[0].w,
                              yv[1].x, yv[1].y, yv[1].z, yv[1].w,
                              yv[2].x, yv[2].y, yv[2].z, yv[2].w};
#pragma unroll
      for (int il = 0; il < NI; ++il) {
#pragma unroll
        for (int cw = 0; cw < 4; ++cw) {
          acc[il][cw] += fabsf(xs[cw] - ywin[cw + 12 - OFF - (I0 + il)]);
        }
      }
    }
    __syncthreads();  // this iter's reads done; next iter may overwrite buf
  }

#undef LOADSS
#undef WRITESS

  // Epilogue: zero out-of-overlap (w,i) pairs, coalesced float4 stores.
#pragma unroll
  for (int il = 0; il < NI; ++il) {
    const int i = I0 + il;
    const int j0 = w0 - i + 12;  // y column used by cw=0
    float4 v;
    v.x = ((unsigned)(j0 + 0) < (unsigned)W_) ? acc[il][0] : 0.0f;
    v.y = ((unsigned)(j0 + 1) < (unsigned)W_) ? acc[il][1] : 0.0f;
    v.z = ((unsigned)(j0 + 2) < (unsigned)W_) ? acc[il][2] : 0.0f;
    v.w = ((unsigned)(j0 + 3) < (unsigned)W_) ? acc[il][3] : 0.0f;
    *reinterpret_cast<float4*>(op + (size_t)i * CH) = v;
  }
}

__global__ __launch_bounds__(512, 6) void rescost_kernel(
    const float* __restrict__ x, const float* __restrict__ y,
    float* __restrict__ out) {
  __shared__ __align__(16) float lds[2 * LDS_BUF];  // 32 KB double buffer

  const int tid = threadIdx.x;
  const int t = tid & 127;   // column group
  const int g = tid >> 7;    // disparity group == staging role (wave-uniform)
  const int r = blockIdx.x;  // row in [0, N*H)
  const int n = r >> 8;      // H = 256
  const int h = r & (H_ - 1);
  const int w0 = t << 2;

  // 3 clamped 16B-aligned y-window offsets; base = w0 + OFF[g]. Each float4
  // window is fully in [0,W) or fully OOB (base mult of 4); clamped windows
  // only feed epilogue-zeroed outputs. Offsets index LDS rows (= y columns).
  const int off_tab[4] = {4, 0, -8, -12};
  const int ybase = w0 + off_tab[g];
  int yoff[3];
#pragma unroll
  for (int k = 0; k < 3; ++k) {
    int idx = ybase + 4 * k;
    idx = idx < 0 ? 0 : idx;
    idx = idx > (W_ - 4) ? (W_ - 4) : idx;
    yoff[k] = idx;
  }

  const size_t row_base = ((size_t)n * C_ * H_ + (size_t)h) * W_;
  const float* xs_ = x + row_base + 4 * t;  // staging src if ARR==0
  const float* ys_ = y + row_base + 4 * t;  // staging src if ARR==1
  float* op = out + ((size_t)n * DISP_ * H_ + (size_t)h) * W_ + w0;

  if (g == 0)
    body<0>(xs_, op, lds, yoff, w0, t);
  else if (g == 1)
    body<1>(ys_, op, lds, yoff, w0, t);
  else if (g == 2)
    body<2>(xs_, op, lds, yoff, w0, t);
  else
    body<3>(ys_, op, lds, yoff, w0, t);
}

extern "C" void kernel_launch(void* const* d_in, const int* in_sizes, int n_in,
                              void* d_out, int out_size, void* d_ws, size_t ws_size,
                              hipStream_t stream) {
  const float* x = (const float*)d_in[0];
  const float* y = (const float*)d_in[1];
  float* out = (float*)d_out;
  dim3 grid(N_ * H_);  // one (n,h) row per block
  dim3 block(512);
  hipLaunchKernelGGL(rescost_kernel, grid, block, 0, stream, x, y, out);
}

// Round 8
// 123.732 us; speedup vs baseline: 2.1566x; 2.1566x over previous
//
#include <hip/hip_runtime.h>

namespace {
constexpr int N_ = 8, C_ = 32, H_ = 256, W_ = 512, DISP_ = 25;
constexpr int CH = H_ * W_;  // elements between channels / disparities
}

// 8-columns-per-thread, 2-way disparity split. 256 threads/block = 2 rows.
//   t  = tid & 63        -> 8 output columns (w0 = 8t; 64 thr cover W=512)
//   dg = (tid >> 6) & 1  -> disparity group (wave-uniform): 0 -> i in [0,13),
//                           1 -> i in [13,25)
//   row = tid >> 7       -> which of the block's 2 rows
// Rationale (round-8): kernel is L1/VMEM-bound on redundant y-window reads.
// 8 cols raises updates-per-loaded-float from 2.6 to 3.6 (28 floats -> ~100
// updates). Register est: acc 104 + ywin 20 + x 8 + addr ~15 = ~147, cap 256
// under launch_bounds(256,2) -> margin >100 (rounds 3/6/7 post-mortem: spill
// whenever est within ~10 of cap; WRITE_SIZE is the spill detector).
// No LDS, no barriers (both LDS attempts spilled); TLP + ILP hide latency.
//
// y window: ywin[m] = y[base + m], base = w0 - 12*dg, m = cw + 12 - il - dg
// (i = 13*dg + il), all compile-time indices in [0,20). 5 float4 blocks at
// base+4k; every block is fully in [0,W) or fully OOB (base mult of 4, W mult
// of 4); clamped (garbage) blocks only feed epilogue-zeroed outputs.
template <int DG>
__device__ __forceinline__ void body(const float* __restrict__ xp,
                                     const float* __restrict__ yp,
                                     float* __restrict__ op,
                                     const int* yoff, int w0) {
  constexpr int NI = 13 - DG;       // 13 or 12 disparities
  constexpr int I0 = 13 * DG;

  float acc[NI][8];
#pragma unroll
  for (int il = 0; il < NI; ++il)
#pragma unroll
    for (int cw = 0; cw < 8; ++cw) acc[il][cw] = 0.0f;

#pragma unroll 1
  for (int c = 0; c < C_; ++c) {
    float4 yv[5];
#pragma unroll
    for (int k = 0; k < 5; ++k)
      yv[k] = *reinterpret_cast<const float4*>(yp + yoff[k]);
    const float4 xa = *reinterpret_cast<const float4*>(xp);
    const float4 xb = *reinterpret_cast<const float4*>(xp + 4);

    const float xs[8] = {xa.x, xa.y, xa.z, xa.w, xb.x, xb.y, xb.z, xb.w};
    const float ywin[20] = {yv[0].x, yv[0].y, yv[0].z, yv[0].w,
                            yv[1].x, yv[1].y, yv[1].z, yv[1].w,
                            yv[2].x, yv[2].y, yv[2].z, yv[2].w,
                            yv[3].x, yv[3].y, yv[3].z, yv[3].w,
                            yv[4].x, yv[4].y, yv[4].z, yv[4].w};

#pragma unroll
    for (int il = 0; il < NI; ++il) {
#pragma unroll
      for (int cw = 0; cw < 8; ++cw) {
        acc[il][cw] += fabsf(xs[cw] - ywin[cw + 12 - il - DG]);
      }
    }

    xp += CH;
    yp += CH;
  }

  // Epilogue: zero out-of-overlap (w,i) pairs; two float4 stores per i.
#pragma unroll
  for (int il = 0; il < NI; ++il) {
    const int i = I0 + il;
    const int j0 = w0 - i + 12;  // y column used by cw=0
    float4 a, b;
    a.x = ((unsigned)(j0 + 0) < (unsigned)W_) ? acc[il][0] : 0.0f;
    a.y = ((unsigned)(j0 + 1) < (unsigned)W_) ? acc[il][1] : 0.0f;
    a.z = ((unsigned)(j0 + 2) < (unsigned)W_) ? acc[il][2] : 0.0f;
    a.w = ((unsigned)(j0 + 3) < (unsigned)W_) ? acc[il][3] : 0.0f;
    b.x = ((unsigned)(j0 + 4) < (unsigned)W_) ? acc[il][4] : 0.0f;
    b.y = ((unsigned)(j0 + 5) < (unsigned)W_) ? acc[il][5] : 0.0f;
    b.z = ((unsigned)(j0 + 6) < (unsigned)W_) ? acc[il][6] : 0.0f;
    b.w = ((unsigned)(j0 + 7) < (unsigned)W_) ? acc[il][7] : 0.0f;
    *reinterpret_cast<float4*>(op + (size_t)i * CH) = a;
    *reinterpret_cast<float4*>(op + (size_t)i * CH + 4) = b;
  }
}

__global__ __launch_bounds__(256, 2) void rescost_kernel(
    const float* __restrict__ x, const float* __restrict__ y,
    float* __restrict__ out) {
  const int tid = threadIdx.x;
  const int t = tid & 63;           // column group: w0 = 8t
  const int dg = (tid >> 6) & 1;    // disparity group (wave-uniform)
  const int row = tid >> 7;         // block covers 2 rows
  const int r = (blockIdx.x << 1) | row;  // row in [0, N*H)
  const int n = r >> 8;                   // H = 256
  const int h = r & (H_ - 1);
  const int w0 = t << 3;

  // 5 clamped 16B-aligned y-window block offsets; base = w0 - 12*dg.
  int yoff[5];
  const int ybase = w0 - 12 * dg;
#pragma unroll
  for (int k = 0; k < 5; ++k) {
    int idx = ybase + 4 * k;
    idx = idx < 0 ? 0 : idx;
    idx = idx > (W_ - 4) ? (W_ - 4) : idx;
    yoff[k] = idx;
  }

  const size_t row_base = ((size_t)n * C_ * H_ + (size_t)h) * W_;
  const float* xp = x + row_base + w0;
  const float* yp = y + row_base;
  float* op = out + ((size_t)n * DISP_ * H_ + (size_t)h) * W_ + w0;

  if (dg == 0)
    body<0>(xp, yp, op, yoff, w0);
  else
    body<1>(xp, yp, op, yoff, w0);
}

extern "C" void kernel_launch(void* const* d_in, const int* in_sizes, int n_in,
                              void* d_out, int out_size, void* d_ws, size_t ws_size,
                              hipStream_t stream) {
  const float* x = (const float*)d_in[0];
  const float* y = (const float*)d_in[1];
  float* out = (float*)d_out;
  dim3 grid(N_ * H_ / 2);  // 2 rows per 256-thread block
  dim3 block(256);
  hipLaunchKernelGGL(rescost_kernel, grid, block, 0, stream, x, y, out);
}

// Round 9
// 84.649 us; speedup vs baseline: 3.1523x; 1.4617x over previous
//
#include <hip/hip_runtime.h>

namespace {
constexpr int N_ = 8, C_ = 32, H_ = 256, W_ = 512, DISP_ = 25;
constexpr int CH = H_ * W_;  // elements between channels / disparities
}

typedef const __attribute__((address_space(1))) void gas_t;  // global
typedef __attribute__((address_space(3))) void las_t;        // LDS

// LDS-staged via global_load_lds (zero staging registers — rounds 6/7 spilled
// because reg-staged LDS writes kept float4 state live across barriers).
// 256 threads/block = one (n,h) row, grid = N*H.
//   t  = tid & 127 -> 4 output columns (w0 = 4t)
//   dg = tid >> 7  -> disparity group (wave-uniform): 0 -> i in [0,13),
//                     1 -> i in [13,25)
//   wv = tid >> 6  -> staging role: wv 0,1 stage x halves; 2,3 stage y halves.
// LDS: 2 buffers x (x row 512 | y row 512) = 8 KB. Per channel each wave
// issues ONE global_load_lds_dwordx4 (wave-uniform LDS base + lane*16 ==
// exactly our linear layout). Pipeline: issue stage(c+1) -> compute(c) from
// LDS -> __syncthreads() (its implicit vmcnt(0) drain completes stage(c+1);
// the barrier also orders buffer reuse). Global traffic = compulsory 4 KB
// per block-channel (round 4 moved 20 KB -> 5x redundancy eliminated).
// Register est: acc 52 + ywin/xs 20 + addr ~20 = ~92; launch_bounds(256,3)
// cap ~170 satisfies est <= cap-40 (spill rule from rounds 3/6/7; WRITE_SIZE
// is the spill detector).
template <int DG>
__device__ __forceinline__ void body(const float* __restrict__ sbase,
                                     float* __restrict__ op, float* lds,
                                     int lds_woff, const int* yoff, int w0) {
  constexpr int NI = 13 - DG;  // 13 or 12 disparities
  constexpr int I0 = 13 * DG;

  float acc[NI][4];
#pragma unroll
  for (int il = 0; il < NI; ++il)
#pragma unroll
    for (int cw = 0; cw < 4; ++cw) acc[il][cw] = 0.0f;

#define STAGE(c, buf)                                                     \
  __builtin_amdgcn_global_load_lds(                                       \
      (gas_t*)(sbase + (size_t)(c)*CH),                                   \
      (las_t*)(lds + (buf)*1024 + lds_woff), 16, 0, 0)

  // Prologue: stage channel 0 into buffer 0; drain + barrier.
  STAGE(0, 0);
  __syncthreads();

#pragma unroll 2
  for (int c = 0; c < C_; ++c) {
    if (c + 1 < C_) STAGE(c + 1, (c + 1) & 1);

    const float* lx = lds + (c & 1) * 1024;  // x row (512 floats)
    const float* ly = lx + 512;              // y row (512 floats)
    const float4 xv = *reinterpret_cast<const float4*>(lx + w0);
    float4 yv[4];
#pragma unroll
    for (int k = 0; k < 4; ++k)
      yv[k] = *reinterpret_cast<const float4*>(ly + yoff[k]);

    const float xs[4] = {xv.x, xv.y, xv.z, xv.w};
    const float ywin[16] = {yv[0].x, yv[0].y, yv[0].z, yv[0].w,
                            yv[1].x, yv[1].y, yv[1].z, yv[1].w,
                            yv[2].x, yv[2].y, yv[2].z, yv[2].w,
                            yv[3].x, yv[3].y, yv[3].z, yv[3].w};
#pragma unroll
    for (int il = 0; il < NI; ++il) {
#pragma unroll
      for (int cw = 0; cw < 4; ++cw) {
        acc[il][cw] += fabsf(xs[cw] - ywin[cw + 12 - DG - il]);
      }
    }

    __syncthreads();  // drains stage(c+1) (vmcnt 0) + orders buffer reuse
  }
#undef STAGE

  // Epilogue: zero out-of-overlap (w,i) pairs, coalesced float4 stores.
#pragma unroll
  for (int il = 0; il < NI; ++il) {
    const int i = I0 + il;
    const int j0 = w0 - i + 12;  // y column used by cw=0
    float4 v;
    v.x = ((unsigned)(j0 + 0) < (unsigned)W_) ? acc[il][0] : 0.0f;
    v.y = ((unsigned)(j0 + 1) < (unsigned)W_) ? acc[il][1] : 0.0f;
    v.z = ((unsigned)(j0 + 2) < (unsigned)W_) ? acc[il][2] : 0.0f;
    v.w = ((unsigned)(j0 + 3) < (unsigned)W_) ? acc[il][3] : 0.0f;
    *reinterpret_cast<float4*>(op + (size_t)i * CH) = v;
  }
}

__global__ __launch_bounds__(256, 3) void rescost_kernel(
    const float* __restrict__ x, const float* __restrict__ y,
    float* __restrict__ out) {
  __shared__ __align__(16) float lds[2 * 1024];  // 8 KB double buffer

  const int tid = threadIdx.x;
  const int t = tid & 127;    // column group (compute)
  const int dg = tid >> 7;    // disparity group (wave-uniform)
  const int wv = tid >> 6;    // wave id = staging role (wave-uniform)
  const int lane = tid & 63;
  const int r = blockIdx.x;   // row in [0, N*H)
  const int n = r >> 8;       // H = 256
  const int h = r & (H_ - 1);
  const int w0 = t << 2;

  // Staging: wave wv stages floats [ (wv&1)*256 , +256 ) of row (x if wv<2
  // else y). Global src is per-lane (lane*4 floats); LDS dest is the wave's
  // base (HW adds lane*16 bytes). lds layout per buffer: x [0,512) y [512,1024).
  const size_t row_base = ((size_t)n * C_ * H_ + (size_t)h) * W_;
  const float* sbase =
      ((wv < 2) ? x : y) + row_base + ((wv & 1) << 8) + (lane << 2);
  const int lds_woff = ((wv >> 1) << 9) + ((wv & 1) << 8);  // floats

  // 4 clamped 16B-aligned y-window offsets (LDS-row indices, cols of y);
  // base = w0 - 12*dg. Each float4 window is fully in [0,W) or fully OOB
  // (base mult of 4); clamped windows only feed epilogue-zeroed outputs.
  int yoff[4];
  const int ybase = w0 - 12 * dg;
#pragma unroll
  for (int k = 0; k < 4; ++k) {
    int idx = ybase + 4 * k;
    idx = idx < 0 ? 0 : idx;
    idx = idx > (W_ - 4) ? (W_ - 4) : idx;
    yoff[k] = idx;
  }

  float* op = out + ((size_t)n * DISP_ * H_ + (size_t)h) * W_ + w0;

  if (dg == 0)
    body<0>(sbase, op, lds, lds_woff, yoff, w0);
  else
    body<1>(sbase, op, lds, lds_woff, yoff, w0);
}

extern "C" void kernel_launch(void* const* d_in, const int* in_sizes, int n_in,
                              void* d_out, int out_size, void* d_ws, size_t ws_size,
                              hipStream_t stream) {
  const float* x = (const float*)d_in[0];
  const float* y = (const float*)d_in[1];
  float* out = (float*)d_out;
  dim3 grid(N_ * H_);  // one (n,h) row per block
  dim3 block(256);
  hipLaunchKernelGGL(rescost_kernel, grid, block, 0, stream, x, y, out);
}

// Round 10
// 82.616 us; speedup vs baseline: 3.2299x; 1.0246x over previous
//
#include <hip/hip_runtime.h>

namespace {
constexpr int N_ = 8, C_ = 32, H_ = 256, W_ = 512, DISP_ = 25;
constexpr int CH = H_ * W_;  // elements between channels / disparities
}

typedef const __attribute__((address_space(1))) void gas_t;  // global
typedef __attribute__((address_space(3))) void las_t;        // LDS

// LDS staging via global_load_lds + depth-2 pipeline with counted vmcnt
// (T3/T4). Round-9 post-mortem: __syncthreads() drains vmcnt(0) -> each
// channel serially exposes ~500-700 cyc of stage latency (VALUBusy 44%).
// Here: raw s_barrier preceded by s_waitcnt vmcnt(1); stage(c+2) issued per
// iter; loads complete ~2 iterations (~1600 cyc) after issue -> hidden.
// 4 LDS buffers (16 KB): stage(c+2) writes buf (c+2)&3 whose last readers
// (iter c-2) are two barriers upstream.
//
// 256 threads/block = one (n,h) row, grid = N*H.
//   t  = tid & 127 -> 4 output columns (w0 = 4t)
//   dg = tid >> 7  -> disparity group (wave-uniform): i in [0,13) / [13,25)
//   wv = tid >> 6  -> staging role: wv 0,1 stage x halves; 2,3 stage y halves
// Per channel each wave issues ONE global_load_lds_dwordx4 (wave-uniform LDS
// base + lane*16 == linear layout). Global traffic = compulsory minimum.
// Registers: acc 52 + ywin/xs 20 + addr ~20 = ~92 (round-9 measured 60 VGPR;
// WRITE_SIZE is the spill detector, rule: est <= cap-40).
template <int DG>
__device__ __forceinline__ void body(const float* __restrict__ sbase,
                                     float* __restrict__ op, float* lds,
                                     int lds_woff, const int* yoff, int w0) {
  constexpr int NI = 13 - DG;  // 13 or 12 disparities
  constexpr int I0 = 13 * DG;

  float acc[NI][4];
#pragma unroll
  for (int il = 0; il < NI; ++il)
#pragma unroll
    for (int cw = 0; cw < 4; ++cw) acc[il][cw] = 0.0f;

#define STAGE(c)                                                          \
  __builtin_amdgcn_global_load_lds(                                       \
      (gas_t*)(sbase + (size_t)(c)*CH),                                   \
      (las_t*)(lds + ((c)&3) * 1024 + lds_woff), 16, 0, 0)

#define COMPUTE(c)                                                        \
  do {                                                                    \
    const float* lx = lds + ((c)&3) * 1024; /* x row (512 floats) */      \
    const float* ly = lx + 512;             /* y row (512 floats) */      \
    const float4 xv = *reinterpret_cast<const float4*>(lx + w0);          \
    float4 yv[4];                                                         \
    _Pragma("unroll") for (int k = 0; k < 4; ++k) yv[k] =                 \
        *reinterpret_cast<const float4*>(ly + yoff[k]);                   \
    const float xs[4] = {xv.x, xv.y, xv.z, xv.w};                         \
    const float ywin[16] = {yv[0].x, yv[0].y, yv[0].z, yv[0].w,           \
                            yv[1].x, yv[1].y, yv[1].z, yv[1].w,           \
                            yv[2].x, yv[2].y, yv[2].z, yv[2].w,           \
                            yv[3].x, yv[3].y, yv[3].z, yv[3].w};          \
    _Pragma("unroll") for (int il = 0; il < NI; ++il) {                   \
      _Pragma("unroll") for (int cw = 0; cw < 4; ++cw) {                  \
        acc[il][cw] += fabsf(xs[cw] - ywin[cw + 12 - DG - il]);           \
      }                                                                   \
    }                                                                     \
  } while (0)

  // Prologue: two stages in flight.
  STAGE(0);
  STAGE(1);

#pragma unroll 1
  for (int c = 0; c < C_ - 1; ++c) {
    // Complete stage(c) (leave stage(c+1) in flight), block-wide.
    asm volatile("s_waitcnt vmcnt(1)" ::: "memory");
    __builtin_amdgcn_s_barrier();
    if (c + 2 < C_) STAGE(c + 2);
    COMPUTE(c);
  }
  // Final channel: only stage(C-1) outstanding -> drain fully.
  asm volatile("s_waitcnt vmcnt(0)" ::: "memory");
  __builtin_amdgcn_s_barrier();
  COMPUTE(C_ - 1);

#undef STAGE
#undef COMPUTE

  // Epilogue: zero out-of-overlap (w,i) pairs, coalesced float4 stores.
#pragma unroll
  for (int il = 0; il < NI; ++il) {
    const int i = I0 + il;
    const int j0 = w0 - i + 12;  // y column used by cw=0
    float4 v;
    v.x = ((unsigned)(j0 + 0) < (unsigned)W_) ? acc[il][0] : 0.0f;
    v.y = ((unsigned)(j0 + 1) < (unsigned)W_) ? acc[il][1] : 0.0f;
    v.z = ((unsigned)(j0 + 2) < (unsigned)W_) ? acc[il][2] : 0.0f;
    v.w = ((unsigned)(j0 + 3) < (unsigned)W_) ? acc[il][3] : 0.0f;
    *reinterpret_cast<float4*>(op + (size_t)i * CH) = v;
  }
}

__global__ __launch_bounds__(256, 3) void rescost_kernel(
    const float* __restrict__ x, const float* __restrict__ y,
    float* __restrict__ out) {
  __shared__ __align__(16) float lds[4 * 1024];  // 16 KB, 4 buffers

  const int tid = threadIdx.x;
  const int t = tid & 127;    // column group (compute)
  const int dg = tid >> 7;    // disparity group (wave-uniform)
  const int wv = tid >> 6;    // wave id = staging role (wave-uniform)
  const int lane = tid & 63;
  const int r = blockIdx.x;   // row in [0, N*H)
  const int n = r >> 8;       // H = 256
  const int h = r & (H_ - 1);
  const int w0 = t << 2;

  // Staging: wave wv stages floats [(wv&1)*256, +256) of row (x if wv<2 else
  // y). Global src per-lane (lane*4 floats); LDS dest = wave base (+lane*16B).
  // Per-buffer layout: x [0,512) | y [512,1024).
  const size_t row_base = ((size_t)n * C_ * H_ + (size_t)h) * W_;
  const float* sbase =
      ((wv < 2) ? x : y) + row_base + ((wv & 1) << 8) + (lane << 2);
  const int lds_woff = ((wv >> 1) << 9) + ((wv & 1) << 8);  // floats

  // 4 clamped 16B-aligned y-window offsets; base = w0 - 12*dg. Each float4
  // window is fully in [0,W) or fully OOB (base mult of 4); clamped windows
  // only feed epilogue-zeroed outputs.
  int yoff[4];
  const int ybase = w0 - 12 * dg;
#pragma unroll
  for (int k = 0; k < 4; ++k) {
    int idx = ybase + 4 * k;
    idx = idx < 0 ? 0 : idx;
    idx = idx > (W_ - 4) ? (W_ - 4) : idx;
    yoff[k] = idx;
  }

  float* op = out + ((size_t)n * DISP_ * H_ + (size_t)h) * W_ + w0;

  if (dg == 0)
    body<0>(sbase, op, lds, lds_woff, yoff, w0);
  else
    body<1>(sbase, op, lds, lds_woff, yoff, w0);
}

extern "C" void kernel_launch(void* const* d_in, const int* in_sizes, int n_in,
                              void* d_out, int out_size, void* d_ws, size_t ws_size,
                              hipStream_t stream) {
  const float* x = (const float*)d_in[0];
  const float* y = (const float*)d_in[1];
  float* out = (float*)d_out;
  dim3 grid(N_ * H_);  // one (n,h) row per block
  dim3 block(256);
  hipLaunchKernelGGL(rescost_kernel, grid, block, 0, stream, x, y, out);
}

// Round 11
// 81.337 us; speedup vs baseline: 3.2807x; 1.0157x over previous
//
#include <hip/hip_runtime.h>

namespace {
constexpr int N_ = 8, C_ = 32, H_ = 256, W_ = 512, DISP_ = 25;
constexpr int CH = H_ * W_;  // elements between channels / disparities
constexpr int NSS = C_ / 2;  // 16 supersteps of 2 channels
}

typedef const __attribute__((address_space(1))) void gas_t;  // global
typedef __attribute__((address_space(3))) void las_t;        // LDS

// LDS staging via global_load_lds, 2-channel supersteps, depth-2 counted
// vmcnt. Round-10 post-mortem: per-barrier phase had only ~208 compute
// cycles/wave vs ~200-300 fixed phase overhead (barrier spread + ds latency)
// -> VALUBusy stuck at 44%. Fix: 2 channels per barrier (416 cyc/wave/phase,
// 16 barriers instead of 32) + launch_bounds(256,4) (measured usage 60 VGPR
// + 52 acc = 112 <= 128 cap -> 4 waves/SIMD, no spill expected; WRITE_SIZE
// is the spill tripwire).
//
// 256 threads/block = one (n,h) row, grid = N*H.
//   t  = tid & 127 -> 4 output columns (w0 = 4t)
//   dg = tid >> 7  -> disparity group (wave-uniform): i in [0,13) / [13,25)
//   wv = tid >> 6  -> staging role: wv 0,1 stage x halves; 2,3 stage y halves
// Per superstep each wave issues TWO global_load_lds_dwordx4 (channels 2s,
// 2s+1; wave-uniform LDS base + lane*16 == linear layout). Buffer layout
// (2048 floats): ch0 x[0,512) y[512,1024) | ch1 x[1024,1536) y[1536,2048).
// Steady state: vmcnt(2) completes superstep s's 2 loads, leaves s+1's two
// in flight; s_barrier makes it block-wide; issue stage(s+2); compute s.
// stage(s+2) writes buf (s+2)&3 whose last readers are 2 barriers upstream.
template <int DG>
__device__ __forceinline__ void body(const float* __restrict__ sbase,
                                     float* __restrict__ op, float* lds,
                                     int lds_woff, const int* yoff, int w0) {
  constexpr int NI = 13 - DG;  // 13 or 12 disparities
  constexpr int I0 = 13 * DG;

  float acc[NI][4];
#pragma unroll
  for (int il = 0; il < NI; ++il)
#pragma unroll
    for (int cw = 0; cw < 4; ++cw) acc[il][cw] = 0.0f;

#define STAGE(s)                                                          \
  do {                                                                    \
    __builtin_amdgcn_global_load_lds(                                     \
        (gas_t*)(sbase + (size_t)(2 * (s)) * CH),                         \
        (las_t*)(lds + ((s)&3) * 2048 + lds_woff), 16, 0, 0);             \
    __builtin_amdgcn_global_load_lds(                                     \
        (gas_t*)(sbase + (size_t)(2 * (s) + 1) * CH),                     \
        (las_t*)(lds + ((s)&3) * 2048 + 1024 + lds_woff), 16, 0, 0);      \
  } while (0)

#define COMPUTE1(base)                                                    \
  do {                                                                    \
    const float* lx = (base);       /* x row (512 floats) */              \
    const float* ly = (base) + 512; /* y row (512 floats) */              \
    const float4 xv = *reinterpret_cast<const float4*>(lx + w0);          \
    float4 yv[4];                                                         \
    _Pragma("unroll") for (int k = 0; k < 4; ++k) yv[k] =                 \
        *reinterpret_cast<const float4*>(ly + yoff[k]);                   \
    const float xs[4] = {xv.x, xv.y, xv.z, xv.w};                         \
    const float ywin[16] = {yv[0].x, yv[0].y, yv[0].z, yv[0].w,           \
                            yv[1].x, yv[1].y, yv[1].z, yv[1].w,           \
                            yv[2].x, yv[2].y, yv[2].z, yv[2].w,           \
                            yv[3].x, yv[3].y, yv[3].z, yv[3].w};          \
    _Pragma("unroll") for (int il = 0; il < NI; ++il) {                   \
      _Pragma("unroll") for (int cw = 0; cw < 4; ++cw) {                  \
        acc[il][cw] += fabsf(xs[cw] - ywin[cw + 12 - DG - il]);           \
      }                                                                   \
    }                                                                     \
  } while (0)

#define COMPUTE2(s)                                                       \
  do {                                                                    \
    const float* bp = lds + ((s)&3) * 2048;                               \
    COMPUTE1(bp);                                                         \
    COMPUTE1(bp + 1024);                                                  \
  } while (0)

  // Prologue: two supersteps (4 loads) in flight.
  STAGE(0);
  STAGE(1);

#pragma unroll 1
  for (int s = 0; s < NSS - 1; ++s) {
    // Complete superstep s's 2 loads; leave s+1's two in flight.
    asm volatile("s_waitcnt vmcnt(2)" ::: "memory");
    __builtin_amdgcn_s_barrier();
    if (s + 2 < NSS) STAGE(s + 2);
    COMPUTE2(s);
  }
  // Final superstep: drain fully.
  asm volatile("s_waitcnt vmcnt(0)" ::: "memory");
  __builtin_amdgcn_s_barrier();
  COMPUTE2(NSS - 1);

#undef STAGE
#undef COMPUTE1
#undef COMPUTE2

  // Epilogue: zero out-of-overlap (w,i) pairs, coalesced float4 stores.
#pragma unroll
  for (int il = 0; il < NI; ++il) {
    const int i = I0 + il;
    const int j0 = w0 - i + 12;  // y column used by cw=0
    float4 v;
    v.x = ((unsigned)(j0 + 0) < (unsigned)W_) ? acc[il][0] : 0.0f;
    v.y = ((unsigned)(j0 + 1) < (unsigned)W_) ? acc[il][1] : 0.0f;
    v.z = ((unsigned)(j0 + 2) < (unsigned)W_) ? acc[il][2] : 0.0f;
    v.w = ((unsigned)(j0 + 3) < (unsigned)W_) ? acc[il][3] : 0.0f;
    *reinterpret_cast<float4*>(op + (size_t)i * CH) = v;
  }
}

__global__ __launch_bounds__(256, 4) void rescost_kernel(
    const float* __restrict__ x, const float* __restrict__ y,
    float* __restrict__ out) {
  __shared__ __align__(16) float lds[4 * 2048];  // 32 KB, 4 superstep buffers

  const int tid = threadIdx.x;
  const int t = tid & 127;    // column group (compute)
  const int dg = tid >> 7;    // disparity group (wave-uniform)
  const int wv = tid >> 6;    // wave id = staging role (wave-uniform)
  const int lane = tid & 63;
  const int r = blockIdx.x;   // row in [0, N*H)
  const int n = r >> 8;       // H = 256
  const int h = r & (H_ - 1);
  const int w0 = t << 2;

  // Staging: wave wv stages floats [(wv&1)*256, +256) of row (x if wv<2 else
  // y). Global src per-lane (lane*4 floats); LDS dest = wave base (+lane*16B).
  const size_t row_base = ((size_t)n * C_ * H_ + (size_t)h) * W_;
  const float* sbase =
      ((wv < 2) ? x : y) + row_base + ((wv & 1) << 8) + (lane << 2);
  const int lds_woff = ((wv >> 1) << 9) + ((wv & 1) << 8);  // floats

  // 4 clamped 16B-aligned y-window offsets; base = w0 - 12*dg. Each float4
  // window is fully in [0,W) or fully OOB (base mult of 4); clamped windows
  // only feed epilogue-zeroed outputs.
  int yoff[4];
  const int ybase = w0 - 12 * dg;
#pragma unroll
  for (int k = 0; k < 4; ++k) {
    int idx = ybase + 4 * k;
    idx = idx < 0 ? 0 : idx;
    idx = idx > (W_ - 4) ? (W_ - 4) : idx;
    yoff[k] = idx;
  }

  float* op = out + ((size_t)n * DISP_ * H_ + (size_t)h) * W_ + w0;

  if (dg == 0)
    body<0>(sbase, op, lds, lds_woff, yoff, w0);
  else
    body<1>(sbase, op, lds, lds_woff, yoff, w0);
}

extern "C" void kernel_launch(void* const* d_in, const int* in_sizes, int n_in,
                              void* d_out, int out_size, void* d_ws, size_t ws_size,
                              hipStream_t stream) {
  const float* x = (const float*)d_in[0];
  const float* y = (const float*)d_in[1];
  float* out = (float*)d_out;
  dim3 grid(N_ * H_);  // one (n,h) row per block
  dim3 block(256);
  hipLaunchKernelGGL(rescost_kernel, grid, block, 0, stream, x, y, out);
}